// Round 8
// baseline (157.489 us; speedup 1.0000x reference)
//
#include <hip/hip_runtime.h>
#include <hip/hip_bf16.h>

#define NPTS 262144
#define DDIM 64
#define KCB  1024
#define PPB 256              // points per block (256 threads, 4 waves x 64 pts)

typedef __attribute__((ext_vector_type(8))) short short8;
typedef __attribute__((ext_vector_type(4))) float f32x4;

static __device__ __forceinline__ unsigned short f2bf_rne(float f) {
    union { float f; unsigned u; } v; v.f = f;
    unsigned r = v.u + 0x7FFFu + ((v.u >> 16) & 1u);
    return (unsigned short)(r >> 16);
}
static __device__ __forceinline__ float bf2f(unsigned short h) {
    union { unsigned u; float f; } v; v.u = ((unsigned)h) << 16;
    return v.f;
}
static __device__ __forceinline__ bool beats(float sa, int ka, float sb, int kb) {
    return (sa > sb) || (sa == sb && ka < kb);
}
static __device__ __forceinline__ float keyf(float acc, unsigned inv) {
    return __uint_as_float((__float_as_uint(acc) & 0xFFFFFFC0u) | inv);  // v_and_or_b32
}

// prep 1: c2n[k] = 256 - 0.5*||c||^2 (all scores positive -> float cmp == u32 cmp)
__global__ __launch_bounds__(256) void c2n_kernel(const float* __restrict__ cb,
                                                  float* __restrict__ c2n) {
    int k = blockIdx.x * blockDim.x + threadIdx.x;
    if (k >= KCB) return;
    const float4* row = (const float4*)(cb + (size_t)k * DDIM);
    float s0 = 0.f, s1 = 0.f, s2 = 0.f, s3 = 0.f;
#pragma unroll
    for (int j = 0; j < DDIM / 4; ++j) {
        float4 a = row[j];
        s0 = __builtin_fmaf(a.x, a.x, s0);
        s1 = __builtin_fmaf(a.y, a.y, s1);
        s2 = __builtin_fmaf(a.z, a.z, s2);
        s3 = __builtin_fmaf(a.w, a.w, s3);
    }
    c2n[k] = 256.0f - 0.5f * ((s0 + s1) + (s2 + s3));
}

// prep 2: flat per-group fragment image for DIRECT global reads (no LDS).
// Group g (16 rows): 4 KB = [ks0 hi 1KB][ks0 lo 1KB][ks1 hi 1KB][ks1 lo 1KB];
// within each 1KB: lane slot = q*256 + col*16 bytes, 8 bf16 elems.
// => per-group reads: base = G + g*4096 + lane*16; imm offsets 0/1024/2048/3072.
__global__ __launch_bounds__(256) void pack_kernel(const float* __restrict__ cb,
                                                   unsigned short* __restrict__ G) {
    int t = blockIdx.x * 256 + threadIdx.x;  // 8192 threads: (row, d8)
    int r = t >> 3, d8 = t & 7;
    const float4* src = (const float4*)(cb + (size_t)r * DDIM + d8 * 8);
    float4 v0 = src[0], v1 = src[1];
    float vv[8] = {v0.x, v0.y, v0.z, v0.w, v1.x, v1.y, v1.z, v1.w};
    short8 h, l;
#pragma unroll
    for (int j = 0; j < 8; ++j) {
        unsigned short hb = f2bf_rne(vv[j]);
        h[j] = (short)hb;
        l[j] = (short)f2bf_rne(vv[j] - bf2f(hb));
    }
    int g = r >> 4, col = r & 15;
    int ks = d8 >> 2, q = d8 & 3;
    size_t base = (size_t)g * 2048 + ks * 1024 + q * 128 + col * 8;  // ushort units
    *(short8*)(G + base) = h;
    *(short8*)(G + base + 512) = l;
}

struct BFrag { short8 h0, l0, h1, l1; };

__global__ __launch_bounds__(256, 2) void vq_main(const float* __restrict__ x,
                                                  const float* __restrict__ cb,
                                                  const float* __restrict__ c2n,
                                                  const unsigned short* __restrict__ G,
                                                  float* __restrict__ out) {
    __shared__ int lds_bk1[PPB];
    __shared__ int lds_bk2[PPB];

    const int tid = threadIdx.x;
    const int lane = tid & 63;
    const int wave = tid >> 6;       // 0..3, each owns 64 points
    const int b15 = lane & 15;
    const int q = lane >> 4;
    const int blk_base = blockIdx.x * PPB;
    const int wave_base = blk_base + wave * 64;
    const unsigned char* Gb = (const unsigned char*)G + lane * 16;

    // ---- A fragments: 4 point-tiles x 2 ksteps x (hi,lo) = 64 VGPR, resident ----
    short8 Ahi[4][2], Alo[4][2];
#pragma unroll
    for (int t = 0; t < 4; ++t) {
        const float* xr = x + (size_t)(wave_base + t * 16 + b15) * DDIM + q * 8;
#pragma unroll
        for (int ks = 0; ks < 2; ++ks) {
            float4 v0 = *(const float4*)(xr + ks * 32);
            float4 v1 = *(const float4*)(xr + ks * 32 + 4);
            float vv[8] = {v0.x, v0.y, v0.z, v0.w, v1.x, v1.y, v1.z, v1.w};
            short8 h, l;
#pragma unroll
            for (int j = 0; j < 8; ++j) {
                unsigned short hb = f2bf_rne(vv[j]);
                h[j] = (short)hb;
                l[j] = (short)f2bf_rne(vv[j] - bf2f(hb));
            }
            Ahi[t][ks] = h;
            Alo[t][ks] = l;
        }
    }

    // top-2 keys per point (16 points/lane), positive-float keys, low6 = 63-group
    float b1[16], b2[16];
#pragma unroll
    for (int i = 0; i < 16; ++i) { b1[i] = 0.0f; b2[i] = 0.0f; }

#define LOADB(dst, g)                                                   \
    {                                                                   \
        const unsigned char* gb_ = Gb + (size_t)(g) * 4096;             \
        (dst).h0 = *(const short8*)(gb_);                               \
        (dst).l0 = *(const short8*)(gb_ + 1024);                        \
        (dst).h1 = *(const short8*)(gb_ + 2048);                        \
        (dst).l1 = *(const short8*)(gb_ + 3072);                        \
    }
    // 24 MFMA (bf16x3 over K=64, 4 tiles); shared cvec as C of each tile's first MFMA
#define COMPUTE(acc, B, cvec)                                                                    \
    {                                                                                            \
        __builtin_amdgcn_s_setprio(1);                                                           \
        _Pragma("unroll") for (int t = 0; t < 4; ++t) {                                          \
            acc[t] = __builtin_amdgcn_mfma_f32_16x16x32_bf16(Ahi[t][0], (B).h0, cvec, 0, 0, 0);  \
            acc[t] = __builtin_amdgcn_mfma_f32_16x16x32_bf16(Ahi[t][0], (B).l0, acc[t], 0, 0, 0);\
            acc[t] = __builtin_amdgcn_mfma_f32_16x16x32_bf16(Alo[t][0], (B).h0, acc[t], 0, 0, 0);\
            acc[t] = __builtin_amdgcn_mfma_f32_16x16x32_bf16(Ahi[t][1], (B).h1, acc[t], 0, 0, 0);\
            acc[t] = __builtin_amdgcn_mfma_f32_16x16x32_bf16(Ahi[t][1], (B).l1, acc[t], 0, 0, 0);\
            acc[t] = __builtin_amdgcn_mfma_f32_16x16x32_bf16(Alo[t][1], (B).h1, acc[t], 0, 0, 0);\
        }                                                                                        \
        __builtin_amdgcn_s_setprio(0);                                                           \
    }
    // one pair (groups 2*pi, 2*pi+1): compute both, reload B for pair pi+2,
    // prefetch c2n for pair pi+2, paired top-2 update straight from acc0/acc1
#define PAIRSTEP(BX, BY, PI, CV0, CV1, NCV0, NCV1)                                  \
    {                                                                               \
        const int pi_ = (PI);                                                       \
        const unsigned inv0 = 63u - (unsigned)(2 * pi_);                            \
        const f32x4 cvec0 = (f32x4){CV0, CV0, CV0, CV0};                            \
        f32x4 acc0[4];                                                              \
        COMPUTE(acc0, BX, cvec0);                                                   \
        LOADB(BX, (2 * pi_ + 4) & 63);                                              \
        const f32x4 cvec1 = (f32x4){CV1, CV1, CV1, CV1};                            \
        f32x4 acc1[4];                                                              \
        COMPUTE(acc1, BY, cvec1);                                                   \
        LOADB(BY, (2 * pi_ + 5) & 63);                                              \
        NCV0 = c2n[((2 * pi_ + 4) & 63) * 16 + b15];                                \
        NCV1 = c2n[((2 * pi_ + 5) & 63) * 16 + b15];                                \
        _Pragma("unroll") for (int t = 0; t < 4; ++t)                               \
            _Pragma("unroll") for (int r = 0; r < 4; ++r) {                         \
                const int i = t * 4 + r;                                            \
                const float ka = keyf(acc0[t][r], inv0);                            \
                const float kb = keyf(acc1[t][r], inv0 - 1u);                       \
                const float med = __builtin_amdgcn_fmed3f(b1[i], ka, kb);           \
                float nb1;                                                          \
                asm("v_max3_f32 %0, %1, %2, %3"                                     \
                    : "=v"(nb1) : "v"(b1[i]), "v"(ka), "v"(kb));                    \
                b1[i] = nb1;                                                        \
                b2[i] = fmaxf(b2[i], med);                                          \
            }                                                                       \
    }

    // ---- prologue: 2 pairs of B-frags + their c2n in flight ----
    BFrag B00, B01, B10, B11;
    LOADB(B00, 0); LOADB(B01, 1); LOADB(B10, 2); LOADB(B11, 3);
    float c00 = c2n[b15],        c01 = c2n[16 + b15];
    float c10 = c2n[32 + b15],   c11 = c2n[48 + b15];
    float c20, c21, c30, c31;

    // ---- main loop: 32 pairs, unrolled by 2, no barriers ----
    for (int gp = 0; gp < 32; gp += 2) {
        PAIRSTEP(B00, B01, gp,     c00, c01, c20, c21);
        PAIRSTEP(B10, B11, gp + 1, c10, c11, c30, c31);
        c00 = c20; c01 = c21; c10 = c30; c11 = c31;
    }
#undef PAIRSTEP
#undef COMPUTE
#undef LOADB

    // ---- decode candidate k, then merge top-2 across the 16 col-lanes ----
    unsigned int K1[16], K2[16];
    int I1[16], I2[16];
#pragma unroll
    for (int i = 0; i < 16; ++i) {
        K1[i] = __float_as_uint(b1[i]); I1[i] = (int)(63u - (K1[i] & 63u)) * 16 + b15;
        K2[i] = __float_as_uint(b2[i]); I2[i] = (int)(63u - (K2[i] & 63u)) * 16 + b15;
    }
#pragma unroll
    for (int m = 1; m < 16; m <<= 1) {
#pragma unroll
        for (int i = 0; i < 16; ++i) {
            unsigned int o1 = __shfl_xor(K1[i], m); int oi1 = __shfl_xor(I1[i], m);
            unsigned int o2 = __shfl_xor(K2[i], m); int oi2 = __shfl_xor(I2[i], m);
            bool ob = (o1 > K1[i]) || (o1 == K1[i] && oi1 < I1[i]);
            unsigned int nk1, nk2; int ni1, ni2;
            if (ob) {
                nk1 = o1; ni1 = oi1;
                bool sb = (K1[i] > o2) || (K1[i] == o2 && I1[i] < oi2);
                nk2 = sb ? K1[i] : o2; ni2 = sb ? I1[i] : oi2;
            } else {
                nk1 = K1[i]; ni1 = I1[i];
                bool sb = (o1 > K2[i]) || (o1 == K2[i] && oi1 < I2[i]);
                nk2 = sb ? o1 : K2[i]; ni2 = sb ? oi1 : I2[i];
            }
            K1[i] = nk1; I1[i] = ni1; K2[i] = nk2; I2[i] = ni2;
        }
    }

    if (b15 == 0) {
#pragma unroll
        for (int t = 0; t < 4; ++t)
#pragma unroll
            for (int r = 0; r < 4; ++r) {
                int pl = wave * 64 + t * 16 + q * 4 + r;
                lds_bk1[pl] = I1[t * 4 + r];
                lds_bk2[pl] = I2[t * 4 + r];
            }
    }
    __syncthreads();

    // ---- exact f32 re-rank of the two candidates + output (proven) ----
    const int p = blk_base + tid;
    const int k1 = lds_bk1[tid], k2 = lds_bk2[tid];
    const float4* xr = (const float4*)(x + (size_t)p * DDIM);
    const float4* c1 = (const float4*)(cb + (size_t)k1 * DDIM);
    const float4* c2r = (const float4*)(cb + (size_t)k2 * DDIM);
    float d1a = 0.f, d1b = 0.f, d2a = 0.f, d2b = 0.f;
#pragma unroll
    for (int j = 0; j < 16; ++j) {
        float4 xv = xr[j];
        float4 u = c1[j], w = c2r[j];
        d1a = __builtin_fmaf(xv.x, u.x, d1a); d1b = __builtin_fmaf(xv.y, u.y, d1b);
        d1a = __builtin_fmaf(xv.z, u.z, d1a); d1b = __builtin_fmaf(xv.w, u.w, d1b);
        d2a = __builtin_fmaf(xv.x, w.x, d2a); d2b = __builtin_fmaf(xv.y, w.y, d2b);
        d2a = __builtin_fmaf(xv.z, w.z, d2a); d2b = __builtin_fmaf(xv.w, w.w, d2b);
    }
    float a1 = (d1a + d1b) + c2n[k1];
    float a2 = (d2a + d2b) + c2n[k2];
    int kf = beats(a1, k1, a2, k2) ? k1 : k2;

    out[p] = (float)kf;
    const float4* cf = (const float4*)(cb + (size_t)kf * DDIM);
    float4* qo = (float4*)(out + NPTS + (size_t)p * DDIM);
#pragma unroll
    for (int j = 0; j < 16; ++j) qo[j] = cf[j];
}

extern "C" void kernel_launch(void* const* d_in, const int* in_sizes, int n_in,
                              void* d_out, int out_size, void* d_ws, size_t ws_size,
                              hipStream_t stream) {
    const float* x = (const float*)d_in[0];
    const float* cb = (const float*)d_in[1];
    float* c2n = (float*)d_ws;                                      // 4 KB
    unsigned short* G = (unsigned short*)((char*)d_ws + 4096);      // 256 KB image

    hipLaunchKernelGGL(c2n_kernel, dim3(KCB / 256), dim3(256), 0, stream, cb, c2n);
    hipLaunchKernelGGL(pack_kernel, dim3(KCB * 8 / 256), dim3(256), 0, stream, cb, G);
    hipLaunchKernelGGL(vq_main, dim3(NPTS / PPB), dim3(256), 0, stream,
                       x, cb, c2n, G, (float*)d_out);
}

// Round 9
// 138.925 us; speedup vs baseline: 1.1336x; 1.1336x over previous
//
#include <hip/hip_runtime.h>
#include <hip/hip_bf16.h>

#define NPTS 262144
#define DDIM 64
#define KCB  1024
#define CHUNK 128            // codebook rows per staged chunk (32 KB image)
#define NCHUNK (KCB / CHUNK) // 8
#define GPC (CHUNK / 16)     // 8 groups (16 cols) per chunk
#define PPB 256              // points per block (512 threads, 8 waves x 32 pts)

typedef __attribute__((ext_vector_type(8))) short short8;
typedef __attribute__((ext_vector_type(4))) float f32x4;

static __device__ __forceinline__ unsigned short f2bf_rne(float f) {
    union { float f; unsigned u; } v; v.f = f;
    unsigned r = v.u + 0x7FFFu + ((v.u >> 16) & 1u);
    return (unsigned short)(r >> 16);
}
static __device__ __forceinline__ float bf2f(unsigned short h) {
    union { unsigned u; float f; } v; v.u = ((unsigned)h) << 16;
    return v.f;
}
static __device__ __forceinline__ bool beats(float sa, int ka, float sb, int kb) {
    return (sa > sb) || (sa == sb && ka < kb);
}
static __device__ __forceinline__ float keyf(float acc, unsigned inv) {
    return __uint_as_float((__float_as_uint(acc) & 0xFFFFFFC0u) | inv);  // v_and_or_b32
}

// prep 1: c2n[k] = 256 - 0.5*||c||^2 (all scores positive -> float cmp == u32 cmp)
__global__ __launch_bounds__(256) void c2n_kernel(const float* __restrict__ cb,
                                                  float* __restrict__ c2n) {
    int k = blockIdx.x * blockDim.x + threadIdx.x;
    if (k >= KCB) return;
    const float4* row = (const float4*)(cb + (size_t)k * DDIM);
    float s0 = 0.f, s1 = 0.f, s2 = 0.f, s3 = 0.f;
#pragma unroll
    for (int j = 0; j < DDIM / 4; ++j) {
        float4 a = row[j];
        s0 = __builtin_fmaf(a.x, a.x, s0);
        s1 = __builtin_fmaf(a.y, a.y, s1);
        s2 = __builtin_fmaf(a.z, a.z, s2);
        s3 = __builtin_fmaf(a.w, a.w, s3);
    }
    c2n[k] = 256.0f - 0.5f * ((s0 + s1) + (s2 + s3));
}

// prep 2: pack codebook into bf16 hi/lo fragment-layout image, 32KB chunks.
// Chunk c (128 rows): ushort[16384] = [hi 8192][lo 8192];
// idx = g*1024 + ks*512 + q*128 + col*8 + j  (row = c*128+g*16+col, d = ks*32+q*8+j)
// => B read for lane l, group g: byte = g*2048 + ks*1024 + l*16 (+16384 for lo)
__global__ __launch_bounds__(256) void pack_kernel(const float* __restrict__ cb,
                                                   unsigned short* __restrict__ G) {
    int t = blockIdx.x * 256 + threadIdx.x;  // 8192 threads: (row, d8)
    int r = t >> 3, d8 = t & 7;
    const float4* src = (const float4*)(cb + (size_t)r * DDIM + d8 * 8);
    float4 v0 = src[0], v1 = src[1];
    float vv[8] = {v0.x, v0.y, v0.z, v0.w, v1.x, v1.y, v1.z, v1.w};
    short8 h, l;
#pragma unroll
    for (int j = 0; j < 8; ++j) {
        unsigned short hb = f2bf_rne(vv[j]);
        h[j] = (short)hb;
        l[j] = (short)f2bf_rne(vv[j] - bf2f(hb));
    }
    int c = r >> 7, g = (r >> 4) & 7, col = r & 15;
    int ks = d8 >> 2, q = d8 & 3;
    size_t base = (size_t)c * 16384 + g * 1024 + ks * 512 + q * 128 + col * 8;
    *(short8*)(G + base) = h;
    *(short8*)(G + base + 8192) = l;
}

struct BFrag { short8 h0, l0, h1, l1; };

__global__ __launch_bounds__(512, 4) void vq_main(const float* __restrict__ x,
                                                  const float* __restrict__ cb,
                                                  const float* __restrict__ c2n,
                                                  const unsigned short* __restrict__ G,
                                                  float* __restrict__ out) {
    __shared__ unsigned short frag[2][CHUNK * DDIM * 2];  // 2 x 32KB double buffer
    __shared__ float lds_c2f[KCB];                        // 4KB: all acc-init values
    __shared__ int lds_bk1[PPB];
    __shared__ int lds_bk2[PPB];

    const int tid = threadIdx.x;
    const int lane = tid & 63;
    const int wave = tid >> 6;       // 0..7
    const int b15 = lane & 15;
    const int q = lane >> 4;
    const int blk_base = blockIdx.x * PPB;
    const int wave_base = blk_base + wave * 32;
    const int lane_off = lane * 16;  // byte offset of this lane's B-fragment slot

    // ---- A fragments: 2 point-tiles x 2 ksteps x (hi,lo) = 32 VGPR, resident ----
    short8 Ahi[2][2], Alo[2][2];
#pragma unroll
    for (int t = 0; t < 2; ++t) {
        const float* xr = x + (size_t)(wave_base + t * 16 + b15) * DDIM + q * 8;
#pragma unroll
        for (int ks = 0; ks < 2; ++ks) {
            float4 v0 = *(const float4*)(xr + ks * 32);
            float4 v1 = *(const float4*)(xr + ks * 32 + 4);
            float vv[8] = {v0.x, v0.y, v0.z, v0.w, v1.x, v1.y, v1.z, v1.w};
            short8 h, l;
#pragma unroll
            for (int j = 0; j < 8; ++j) {
                unsigned short hb = f2bf_rne(vv[j]);
                h[j] = (short)hb;
                l[j] = (short)f2bf_rne(vv[j] - bf2f(hb));
            }
            Ahi[t][ks] = h;
            Alo[t][ks] = l;
        }
    }

    // top-2 keys per point (8 points/lane), positive-float keys, low6 = 63-group
    float b1[8], b2[8];
#pragma unroll
    for (int i = 0; i < 8; ++i) { b1[i] = 0.0f; b2[i] = 0.0f; }

    // stage 32KB chunk: 512 threads x 4 x 16B global_load_lds
#define STAGE(cc, buf)                                                                     \
    {                                                                                      \
        const unsigned char* gsrc = (const unsigned char*)G + (size_t)(cc) * 32768 + tid * 16; \
        unsigned char* ldst = (unsigned char*)&frag[buf][0] + tid * 16;                    \
        _Pragma("unroll") for (int it = 0; it < 4; ++it)                                   \
            __builtin_amdgcn_global_load_lds(                                              \
                (const __attribute__((address_space(1))) unsigned int*)(gsrc + it * 8192), \
                (__attribute__((address_space(3))) unsigned int*)(ldst + it * 8192),       \
                16, 0, 0);                                                                 \
    }
#define LOADB(dst, fb, g)                                               \
    {                                                                   \
        const unsigned char* p_ = (fb) + (size_t)(g) * 2048 + lane_off; \
        (dst).h0 = *(const short8*)(p_);                                \
        (dst).l0 = *(const short8*)(p_ + 16384);                        \
        (dst).h1 = *(const short8*)(p_ + 1024);                         \
        (dst).l1 = *(const short8*)(p_ + 17408);                        \
    }
    // 12 MFMA (bf16x3, K=64, 2 tiles); shared cvec as C of each tile's first MFMA
#define COMPUTE(acc, B, cvec)                                                                    \
    {                                                                                            \
        __builtin_amdgcn_s_setprio(1);                                                           \
        _Pragma("unroll") for (int t = 0; t < 2; ++t) {                                          \
            acc[t] = __builtin_amdgcn_mfma_f32_16x16x32_bf16(Ahi[t][0], (B).h0, cvec, 0, 0, 0);  \
            acc[t] = __builtin_amdgcn_mfma_f32_16x16x32_bf16(Ahi[t][0], (B).l0, acc[t], 0, 0, 0);\
            acc[t] = __builtin_amdgcn_mfma_f32_16x16x32_bf16(Alo[t][0], (B).h0, acc[t], 0, 0, 0);\
            acc[t] = __builtin_amdgcn_mfma_f32_16x16x32_bf16(Ahi[t][1], (B).h1, acc[t], 0, 0, 0);\
            acc[t] = __builtin_amdgcn_mfma_f32_16x16x32_bf16(Ahi[t][1], (B).l1, acc[t], 0, 0, 0);\
            acc[t] = __builtin_amdgcn_mfma_f32_16x16x32_bf16(Alo[t][1], (B).h1, acc[t], 0, 0, 0);\
        }                                                                                        \
        __builtin_amdgcn_s_setprio(0);                                                           \
    }

    // ---- prologue: stage chunk 0; fill c2n LDS table (barrier covers both) ----
    STAGE(0, 0);
    lds_c2f[tid] = c2n[tid];
    lds_c2f[tid + 512] = c2n[tid + 512];
    __syncthreads();

    for (int c = 0; c < NCHUNK; ++c) {
        const int cur = c & 1;
        if (c + 1 < NCHUNK) STAGE(c + 1, cur ^ 1);
        const unsigned char* fb = (const unsigned char*)&frag[cur][0];

        // 4 pairs of groups per chunk; both groups' B issued before MFMA
#pragma unroll
        for (int gp = 0; gp < 4; ++gp) {
            const int g0 = gp * 2, g1 = g0 + 1;
            const unsigned inv0 = 63u - (unsigned)(c * GPC + g0);
            BFrag Ba, Bb;
            LOADB(Ba, fb, g0);
            LOADB(Bb, fb, g1);
            const float cg0 = lds_c2f[(c * GPC + g0) * 16 + b15];
            const float cg1 = lds_c2f[(c * GPC + g1) * 16 + b15];

            f32x4 acc0[2];
            const f32x4 cvec0 = (f32x4){cg0, cg0, cg0, cg0};
            COMPUTE(acc0, Ba, cvec0);
            f32x4 acc1[2];
            const f32x4 cvec1 = (f32x4){cg1, cg1, cg1, cg1};
            COMPUTE(acc1, Bb, cvec1);

#pragma unroll
            for (int t = 0; t < 2; ++t)
#pragma unroll
                for (int r = 0; r < 4; ++r) {
                    const int i = t * 4 + r;
                    const float ka = keyf(acc0[t][r], inv0);
                    const float kb = keyf(acc1[t][r], inv0 - 1u);
                    const float med = __builtin_amdgcn_fmed3f(b1[i], ka, kb);
                    float nb1;
                    asm("v_max3_f32 %0, %1, %2, %3"
                        : "=v"(nb1) : "v"(b1[i]), "v"(ka), "v"(kb));
                    b1[i] = nb1;
                    b2[i] = fmaxf(b2[i], med);
                }
        }
        __syncthreads();  // loads for chunk c+1 landed under compute; safe to flip
    }
#undef STAGE
#undef LOADB
#undef COMPUTE

    // ---- decode candidate k, then merge top-2 across the 16 col-lanes ----
    unsigned int K1[8], K2[8];
    int I1[8], I2[8];
#pragma unroll
    for (int i = 0; i < 8; ++i) {
        K1[i] = __float_as_uint(b1[i]); I1[i] = (int)(63u - (K1[i] & 63u)) * 16 + b15;
        K2[i] = __float_as_uint(b2[i]); I2[i] = (int)(63u - (K2[i] & 63u)) * 16 + b15;
    }
#pragma unroll
    for (int m = 1; m < 16; m <<= 1) {
#pragma unroll
        for (int i = 0; i < 8; ++i) {
            unsigned int o1 = __shfl_xor(K1[i], m); int oi1 = __shfl_xor(I1[i], m);
            unsigned int o2 = __shfl_xor(K2[i], m); int oi2 = __shfl_xor(I2[i], m);
            bool ob = (o1 > K1[i]) || (o1 == K1[i] && oi1 < I1[i]);
            unsigned int nk1, nk2; int ni1, ni2;
            if (ob) {
                nk1 = o1; ni1 = oi1;
                bool sb = (K1[i] > o2) || (K1[i] == o2 && I1[i] < oi2);
                nk2 = sb ? K1[i] : o2; ni2 = sb ? I1[i] : oi2;
            } else {
                nk1 = K1[i]; ni1 = I1[i];
                bool sb = (o1 > K2[i]) || (o1 == K2[i] && oi1 < I2[i]);
                nk2 = sb ? o1 : K2[i]; ni2 = sb ? oi1 : I2[i];
            }
            K1[i] = nk1; I1[i] = ni1; K2[i] = nk2; I2[i] = ni2;
        }
    }

    if (b15 == 0) {
#pragma unroll
        for (int t = 0; t < 2; ++t)
#pragma unroll
            for (int r = 0; r < 4; ++r) {
                int pl = wave * 32 + t * 16 + q * 4 + r;
                lds_bk1[pl] = I1[t * 4 + r];
                lds_bk2[pl] = I2[t * 4 + r];
            }
    }
    __syncthreads();

    // ---- exact f32 re-rank: 2 threads per point, one candidate each ----
    const int pid = tid >> 1;
    const int p = blk_base + pid;
    const int ksel = (tid & 1) ? lds_bk2[pid] : lds_bk1[pid];
    const float4* xr = (const float4*)(x + (size_t)p * DDIM);
    const float4* cr = (const float4*)(cb + (size_t)ksel * DDIM);
    float da = 0.f, db = 0.f;
#pragma unroll
    for (int j = 0; j < 16; ++j) {
        float4 xv = xr[j];
        float4 u = cr[j];
        da = __builtin_fmaf(xv.x, u.x, da); db = __builtin_fmaf(xv.y, u.y, db);
        da = __builtin_fmaf(xv.z, u.z, da); db = __builtin_fmaf(xv.w, u.w, db);
    }
    float a = (da + db) + c2n[ksel];
    float oa = __shfl_xor(a, 1);
    int ok = __shfl_xor(ksel, 1);
    const bool first = ((tid & 1) == 0);
    float a1 = first ? a : oa; int k1 = first ? ksel : ok;
    float a2 = first ? oa : a; int k2 = first ? ok : ksel;
    int kf = beats(a1, k1, a2, k2) ? k1 : k2;

    if (first) out[p] = (float)kf;
    const float4* cf = (const float4*)(cb + (size_t)kf * DDIM + (tid & 1) * 32);
    float4* qo = (float4*)(out + NPTS + (size_t)p * DDIM + (tid & 1) * 32);
#pragma unroll
    for (int j = 0; j < 8; ++j) qo[j] = cf[j];
}

extern "C" void kernel_launch(void* const* d_in, const int* in_sizes, int n_in,
                              void* d_out, int out_size, void* d_ws, size_t ws_size,
                              hipStream_t stream) {
    const float* x = (const float*)d_in[0];
    const float* cb = (const float*)d_in[1];
    float* c2n = (float*)d_ws;                                      // 4 KB
    unsigned short* G = (unsigned short*)((char*)d_ws + 4096);      // 256 KB image

    hipLaunchKernelGGL(c2n_kernel, dim3(KCB / 256), dim3(256), 0, stream, cb, c2n);
    hipLaunchKernelGGL(pack_kernel, dim3(KCB * 8 / 256), dim3(256), 0, stream, cb, G);
    hipLaunchKernelGGL(vq_main, dim3(NPTS / PPB), dim3(512), 0, stream,
                       x, cb, c2n, G, (float*)d_out);
}